// Round 14
// baseline (340.827 us; speedup 1.0000x reference)
//
#include <hip/hip_runtime.h>
#include <hip/hip_bf16.h>
#include <stdint.h>

// GPTQOFTLinear: y = (x @ R_blockdiag) @ W^T + b
// W' = W with each 64-col block right-multiplied by Q_r^T; y = x @ W'^T + b.
// r14: TWO dispatches. prep = [cayley+fold fused per r (blocks 0-63, o-chunk loop)
// || cast_x (blocks 64-2111)]  ->  GEMM (r13: 5-slot ring, 1 barrier/phase, 230us).

typedef __bf16 bf16;
typedef __attribute__((ext_vector_type(4))) __bf16 bf16x4;
typedef __attribute__((ext_vector_type(8))) __bf16 bf16x8;
typedef __attribute__((ext_vector_type(4))) float f32x4;

__device__ __forceinline__ bf16 f2bf(float f) {
  unsigned u = __builtin_bit_cast(unsigned, f);
  u += 0x7fffu + ((u >> 16) & 1u);          // RNE
  unsigned short h = (unsigned short)(u >> 16);
  return __builtin_bit_cast(bf16, h);
}

// ---------------- Kernel 1: prep = cayley+fold (blocks 0-63) || cast (64-2111) --------
// Per r-block: S = 0.5(D-D^T) -> T = order-6 Neumann of (I+S)^{-1} -> Q = (I-S)T
// (kept in LDS as bf16 Xt[k][c]) -> loop 32 o-chunks: stage W(128x64)->bf16 Wb,
// 16 MFMA, write Wp[o, r*64+k] = sum_c W[o,r*64+c] * Q[k][c].
// LDS overlay (50688 B): [St 17408][Ta 16640][Tb 16640]; after cayley: Wb->St-space,
// Xt->Ta-space (Ta dead after iter 4; final T lives in Tb; Q-step reads St+Tb).
__global__ __launch_bounds__(256) void prep_kernel(const float* __restrict__ oft_r,
                                                   const float* __restrict__ W,
                                                   bf16* __restrict__ Wp,
                                                   const float* __restrict__ x,
                                                   bf16* __restrict__ xb, long n) {
  __shared__ char smem[50688];
  const int tid = threadIdx.x;

  if (blockIdx.x >= 64) {
    // ---- cast path ----
    long i0 = ((long)(blockIdx.x - 64) * 256 + tid) * 8;
    long stride = (long)(gridDim.x - 64) * 256 * 8;
    for (long i = i0; i < n; i += stride) {
      f32x4 a = *reinterpret_cast<const f32x4*>(x + i);
      f32x4 b = *reinterpret_cast<const f32x4*>(x + i + 4);
      bf16x8 o;
      o[0] = f2bf(a[0]); o[1] = f2bf(a[1]); o[2] = f2bf(a[2]); o[3] = f2bf(a[3]);
      o[4] = f2bf(b[0]); o[5] = f2bf(b[1]); o[6] = f2bf(b[2]); o[7] = f2bf(b[3]);
      *reinterpret_cast<bf16x8*>(xb + i) = o;
    }
    return;
  }

  // ---- cayley+fold path ----
  float (*St)[68] = reinterpret_cast<float(*)[68]>(smem);          // 17408 B
  float (*Ta)[65] = reinterpret_cast<float(*)[65]>(smem + 17408);  // 16640 B
  float (*Tb)[65] = reinterpret_cast<float(*)[65]>(smem + 34048);  // 16640 B
  bf16* Wb = reinterpret_cast<bf16*>(smem);                        // 16384 B (St-space)
  bf16* Xt = reinterpret_cast<bf16*>(smem + 17408);                //  8192 B (Ta-space)

  const int r = blockIdx.x;
  const float* D = oft_r + (size_t)r * 4096;

  for (int idx = tid; idx < 4096; idx += 256) {
    int i = idx >> 6, j = idx & 63;
    float s = 0.5f * (D[i * 64 + j] - D[j * 64 + i]);
    St[j][i] = s;
    Ta[i][j] = (i == j ? 1.0f : 0.0f) - s;   // T0 = I - S
  }
  __syncthreads();

  const int j = tid & 63;
  const int w = tid >> 6;
  float (*Tin)[65] = Ta;
  float (*Tout)[65] = Tb;

  for (int it = 0; it < 5; ++it) {           // 5 iters: final T (order 6) lands in Tb
    float out[16];
#pragma unroll
    for (int m = 0; m < 16; ++m) out[m] = ((w * 16 + m) == j ? 1.0f : 0.0f);
    for (int c = 0; c < 64; ++c) {
      float tc = Tin[c][j];
      f32x4 s0 = *reinterpret_cast<const f32x4*>(&St[c][w * 16]);
      f32x4 s1 = *reinterpret_cast<const f32x4*>(&St[c][w * 16 + 4]);
      f32x4 s2 = *reinterpret_cast<const f32x4*>(&St[c][w * 16 + 8]);
      f32x4 s3 = *reinterpret_cast<const f32x4*>(&St[c][w * 16 + 12]);
#pragma unroll
      for (int q = 0; q < 4; ++q) {
        out[q]      -= s0[q] * tc;
        out[4 + q]  -= s1[q] * tc;
        out[8 + q]  -= s2[q] * tc;
        out[12 + q] -= s3[q] * tc;
      }
    }
#pragma unroll
    for (int m = 0; m < 16; ++m) Tout[w * 16 + m][j] = out[m];
    __syncthreads();
    float (*tmp)[65] = Tin; Tin = Tout; Tout = tmp;
  }

  // Q = (I - S) * T  (reads St + Tin=Tb), keep in regs
  float qout[16];
  {
#pragma unroll
    for (int m = 0; m < 16; ++m) qout[m] = Tin[w * 16 + m][j];
    for (int c = 0; c < 64; ++c) {
      float tc = Tin[c][j];
      f32x4 s0 = *reinterpret_cast<const f32x4*>(&St[c][w * 16]);
      f32x4 s1 = *reinterpret_cast<const f32x4*>(&St[c][w * 16 + 4]);
      f32x4 s2 = *reinterpret_cast<const f32x4*>(&St[c][w * 16 + 8]);
      f32x4 s3 = *reinterpret_cast<const f32x4*>(&St[c][w * 16 + 12]);
#pragma unroll
      for (int q = 0; q < 4; ++q) {
        qout[q]      -= s0[q] * tc;
        qout[4 + q]  -= s1[q] * tc;
        qout[8 + q]  -= s2[q] * tc;
        qout[12 + q] -= s3[q] * tc;
      }
    }
  }
  __syncthreads();            // all St/Tb reads done; St-space & Ta-space now reusable

  // Xt[k=w*16+m][c=j] = bf16(Q[k][c]) into Ta-space
#pragma unroll
  for (int m = 0; m < 16; ++m) Xt[(w * 16 + m) * 64 + j] = f2bf(qout[m]);

  const int lane = tid & 63;
  const int wave = tid >> 6;
  const int fr = lane & 15;
  const int kg = lane >> 4;
  const int wm = wave * 32;

  for (int oc = 0; oc < 32; ++oc) {
    const int o0 = oc * 128;
    // stage W chunk (128 x 64 f32 -> bf16) into Wb (St-space)
#pragma unroll
    for (int i = 0; i < 8; ++i) {
      int c = i * 256 + tid;
      int row = c >> 4, c4 = c & 15;
      f32x4 v = *reinterpret_cast<const f32x4*>(W + (size_t)(o0 + row) * 4096 + r * 64 + c4 * 4);
      bf16x4 o; o[0] = f2bf(v[0]); o[1] = f2bf(v[1]); o[2] = f2bf(v[2]); o[3] = f2bf(v[3]);
      *reinterpret_cast<bf16x4*>(&Wb[row * 64 + c4 * 4]) = o;
    }
    __syncthreads();

    f32x4 acc[2][4];
#pragma unroll
    for (int mi = 0; mi < 2; ++mi)
#pragma unroll
      for (int ni = 0; ni < 4; ++ni) acc[mi][ni] = (f32x4){0.f, 0.f, 0.f, 0.f};

#pragma unroll
    for (int kk = 0; kk < 64; kk += 32) {
      bf16x8 af[2], bx[4];
#pragma unroll
      for (int mi = 0; mi < 2; ++mi)
        af[mi] = *reinterpret_cast<const bf16x8*>(&Wb[(wm + mi * 16 + fr) * 64 + kk + kg * 8]);
#pragma unroll
      for (int ni = 0; ni < 4; ++ni)
        bx[ni] = *reinterpret_cast<const bf16x8*>(&Xt[(ni * 16 + fr) * 64 + kk + kg * 8]);
#pragma unroll
      for (int mi = 0; mi < 2; ++mi)
#pragma unroll
        for (int ni = 0; ni < 4; ++ni)
          acc[mi][ni] = __builtin_amdgcn_mfma_f32_16x16x32_bf16(af[mi], bx[ni], acc[mi][ni], 0, 0, 0);
    }

#pragma unroll
    for (int mi = 0; mi < 2; ++mi)
#pragma unroll
      for (int ni = 0; ni < 4; ++ni)
#pragma unroll
        for (int q = 0; q < 4; ++q) {
          int row = o0 + wm + mi * 16 + kg * 4 + q;
          int col = ni * 16 + fr;
          Wp[(size_t)row * 4096 + r * 64 + col] = f2bf(acc[mi][ni][q]);
        }
    __syncthreads();          // protect Wb before next o-chunk restage
  }
}

// ---------------- Kernel 2: 256x256 GEMM, 5-slot LDS ring, 1 barrier/phase -----------
// (unchanged from r13 — 230us proven, conflicts 0, absmax stable)
// A=xb [M,K] bf16, B=Wp [N,K] bf16 (B^T layout), C [M,N] f32. 8 waves (2M x 4N).
// Ring: 5 slots x 32KB = 160 KiB. slot(t,ks) = (2t+ks)%5. Stage: P0 A(t+2,ks0),
// P1 B(t+2,ks0), P2 A(t+2,ks1), P3 B(t+2,ks1). Steady vmcnt(12) at P1/P3; tail 8/4, 0.
// Swizzle key (row>>1)&3 (conflict-free). Slot reuse distance 12 phases >> wave skew.

#define GLDS16(g, l) __builtin_amdgcn_global_load_lds( \
    (const __attribute__((address_space(1))) unsigned int*)(g), \
    (__attribute__((address_space(3))) unsigned int*)(l), 16, 0, 0)

#define VMCNT12 asm volatile("s_waitcnt vmcnt(12)" ::: "memory")
#define VMCNT8  asm volatile("s_waitcnt vmcnt(8)" ::: "memory")
#define VMCNT4  asm volatile("s_waitcnt vmcnt(4)" ::: "memory")
#define VMCNT0  asm volatile("s_waitcnt vmcnt(0)" ::: "memory")
#define NOWAIT  do {} while (0)
#define BARRIER() do { asm volatile("" ::: "memory"); \
  __builtin_amdgcn_s_barrier(); asm volatile("" ::: "memory"); } while (0)

#define MFMA16(AF, BF, RB) \
  _Pragma("unroll") \
  for (int m_ = 0; m_ < 4; ++m_) \
    _Pragma("unroll") \
    for (int n_ = 0; n_ < 4; ++n_) \
      acc[RB + m_][n_] = __builtin_amdgcn_mfma_f32_16x16x32_bf16(AF[m_], BF[n_], acc[RB + m_][n_], 0, 0, 0);

#define DO_T(S0, S1, SA, SB, TN, PRE, W2, W1) do { \
    /* P0: ks0 mi0-3; stage A(TN,ks0) */ \
    _Pragma("unroll") for (int n_ = 0; n_ < 4; ++n_) Ob[n_] = LDB(S0, n_); \
    _Pragma("unroll") for (int m_ = 0; m_ < 4; ++m_) Oa[m_] = LDA(S0, m_); \
    if (PRE) STG_A(TN, SA, 0); \
    BARRIER(); \
    __builtin_amdgcn_s_setprio(1); MFMA16(Oa, Ob, 0) __builtin_amdgcn_s_setprio(0); \
    /* P1: ks0 mi4-7; stage B(TN,ks0); W2 publishes (t,ks1) */ \
    _Pragma("unroll") for (int m_ = 0; m_ < 4; ++m_) Ea[m_] = LDA(S0, 4 + m_); \
    if (PRE) STG_B(TN, SA, 0); \
    W2; \
    BARRIER(); \
    __builtin_amdgcn_s_setprio(1); MFMA16(Ea, Ob, 4) __builtin_amdgcn_s_setprio(0); \
    /* P2: ks1 mi0-3; stage A(TN,ks1) */ \
    _Pragma("unroll") for (int n_ = 0; n_ < 4; ++n_) Eb[n_] = LDB(S1, n_); \
    _Pragma("unroll") for (int m_ = 0; m_ < 4; ++m_) Oa[m_] = LDA(S1, m_); \
    if (PRE) STG_A(TN, SB, 1); \
    BARRIER(); \
    __builtin_amdgcn_s_setprio(1); MFMA16(Oa, Eb, 0) __builtin_amdgcn_s_setprio(0); \
    /* P3: ks1 mi4-7; stage B(TN,ks1); W1 publishes (t+1,ks0) */ \
    _Pragma("unroll") for (int m_ = 0; m_ < 4; ++m_) Ea[m_] = LDA(S1, 4 + m_); \
    if (PRE) STG_B(TN, SB, 1); \
    W1; \
    BARRIER(); \
    __builtin_amdgcn_s_setprio(1); MFMA16(Ea, Eb, 4) __builtin_amdgcn_s_setprio(0); \
  } while (0)

__global__ __launch_bounds__(512, 2) void gemm_kernel(const bf16* __restrict__ A,
                                                      const bf16* __restrict__ B,
                                                      const float* __restrict__ bias,
                                                      float* __restrict__ C,
                                                      int M, int N, int K) {
  __shared__ bf16 lds[81920];   // 5 slots x 16384 elems = 160 KiB
  const int tid = threadIdx.x;
  const int lane = tid & 63;
  const int wave = tid >> 6;
  const int wr = wave >> 2;          // 0..1  (M)
  const int wc = wave & 3;           // 0..3  (N)
  const int fr = lane & 15;
  const int kg = lane >> 4;
  const int m0 = blockIdx.y * 256;
  const int n0 = blockIdx.x * 256;

  f32x4 acc[8][4];
#pragma unroll
  for (int m = 0; m < 8; ++m)
#pragma unroll
    for (int n = 0; n < 4; ++n) acc[m][n] = (f32x4){0.f, 0.f, 0.f, 0.f};

  auto STG = [&](const bf16* src, int base_row, int t, int ks, int ldsbase) {
#pragma unroll
    for (int i = 0; i < 2; ++i) {
      int c = i * 512 + tid;           // 1024 chunks of 16B per half-tile
      int row = c >> 2, cc = c & 3;
      const bf16* g = src + (size_t)(base_row + row) * K + t * 64 + ks * 32
                      + ((cc ^ ((row >> 1) & 3)) << 3);      // inverse-swizzled source
      GLDS16(g, &lds[ldsbase + ((i * 512 + wave * 64) << 3)]); // linear dest
    }
  };
  auto STG_A = [&](int t, int slot, int ks) { STG(A, m0, t, ks, slot * 16384); };
  auto STG_B = [&](int t, int slot, int ks) { STG(B, n0, t, ks, slot * 16384 + 8192); };

  auto LDA = [&](int slot, int mi) -> bf16x8 {
    int row = wr * 128 + mi * 16 + fr;
    return *reinterpret_cast<const bf16x8*>(
        &lds[slot * 16384 + row * 32 + ((kg ^ ((row >> 1) & 3)) << 3)]);
  };
  auto LDB = [&](int slot, int ni) -> bf16x8 {
    int row = wc * 64 + ni * 16 + fr;
    return *reinterpret_cast<const bf16x8*>(
        &lds[slot * 16384 + 8192 + row * 32 + ((kg ^ ((row >> 1) & 3)) << 3)]);
  };

  // prologue: stage tiles 0 and 1 in canonical FIFO order; publish (0,ks0).
  STG_A(0, 0, 0); STG_B(0, 0, 0); STG_A(0, 1, 1); STG_B(0, 1, 1);
  STG_A(1, 2, 0); STG_B(1, 2, 0); STG_A(1, 3, 1); STG_B(1, 3, 1);
  VMCNT12;
  BARRIER();

  bf16x8 Oa[4], Ob[4], Ea[4], Eb[4];
  // slots per 5-tile period: p0(0,1) p1(2,3) p2(4,0) p3(1,2) p4(3,4); SA/SB = slots of t+2.
  for (int t = 0; t < 60; t += 5) {
    DO_T(0, 1, 4, 0, t + 2, true, VMCNT12, VMCNT12);
    DO_T(2, 3, 1, 2, t + 3, true, VMCNT12, VMCNT12);
    DO_T(4, 0, 3, 4, t + 4, true, VMCNT12, VMCNT12);
    DO_T(1, 2, 0, 1, t + 5, true, VMCNT12, VMCNT12);
    DO_T(3, 4, 2, 3, t + 6, true, VMCNT12, VMCNT12);
  }
  // tail: tiles 60..63 (NT = 64)
  DO_T(0, 1, 4, 0, 62, true,  VMCNT12, VMCNT12);
  DO_T(2, 3, 1, 2, 63, true,  VMCNT12, VMCNT12);
  DO_T(4, 0, 0, 0, 0,  false, VMCNT8,  VMCNT4);
  DO_T(1, 2, 0, 0, 0,  false, VMCNT0,  NOWAIT);

  // epilogue: D row = kg*4+q (+16*m blocks), col = fr (+16*n)
#pragma unroll
  for (int n = 0; n < 4; ++n) {
    int col = n0 + wc * 64 + n * 16 + fr;
    float bv = bias[col];
#pragma unroll
    for (int m = 0; m < 8; ++m) {
      int row0 = m0 + wr * 128 + m * 16 + kg * 4;
#pragma unroll
      for (int q = 0; q < 4; ++q)
        C[(size_t)(row0 + q) * N + col] = acc[m][n][q] + bv;
    }
  }
}

extern "C" void kernel_launch(void* const* d_in, const int* in_sizes, int n_in,
                              void* d_out, int out_size, void* d_ws, size_t ws_size,
                              hipStream_t stream) {
  const float* x     = (const float*)d_in[0];   // [2,4096,4096]
  const float* oft_r = (const float*)d_in[1];   // [64,64,64]
  const float* W     = (const float*)d_in[2];   // [4096,4096]
  const float* b     = (const float*)d_in[3];   // [4096]
  float* y = (float*)d_out;                     // [8192,4096] f32

  char* ws = (char*)d_ws;
  bf16* Wp = (bf16*)ws;                         // 32 MiB: folded W, bf16
  bf16* xb = (bf16*)(ws + (32u << 20));         // 64 MiB: x, bf16

  prep_kernel<<<2112, 256, 0, stream>>>(oft_r, W, Wp, x, xb, 33554432L);
  dim3 gg(4096 / 256, 8192 / 256);   // (16, 32)
  gemm_kernel<<<gg, 512, 0, stream>>>(xb, Wp, b, y, 8192, 4096, 4096);
}

// Round 15
// 301.811 us; speedup vs baseline: 1.1293x; 1.1293x over previous
//
#include <hip/hip_runtime.h>
#include <hip/hip_bf16.h>
#include <stdint.h>

// GPTQOFTLinear: y = (x @ R_blockdiag) @ W^T + b
// W' = W with each 64-col block right-multiplied by Q_r^T; y = x @ W'^T + b.
// r15 = best-of-each: r12 pipeline (prep = cayley||cast -> fold@2048 -> GEMM) with
// r13's GEMM (5-slot ring, 1 barrier/phase). r14's 64-block fused fold reverted
// (latency-bound tail on 25% of CUs).

typedef __bf16 bf16;
typedef __attribute__((ext_vector_type(4))) __bf16 bf16x4;
typedef __attribute__((ext_vector_type(8))) __bf16 bf16x8;
typedef __attribute__((ext_vector_type(4))) float f32x4;

__device__ __forceinline__ bf16 f2bf(float f) {
  unsigned u = __builtin_bit_cast(unsigned, f);
  u += 0x7fffu + ((u >> 16) & 1u);          // RNE
  unsigned short h = (unsigned short)(u >> 16);
  return __builtin_bit_cast(bf16, h);
}

// ---------------- Kernel 1: prep = cayley (blocks 0-63) || cast_x (blocks 64+) --------
__global__ __launch_bounds__(256) void prep_kernel(const float* __restrict__ oft_r,
                                                   float* __restrict__ Qxt,
                                                   const float* __restrict__ x,
                                                   bf16* __restrict__ xb, long n) {
  __shared__ float St[64][68];
  __shared__ float Ta[64][65];
  __shared__ float Tb[64][65];
  const int tid = threadIdx.x;

  if (blockIdx.x >= 64) {
    long i0 = ((long)(blockIdx.x - 64) * 256 + tid) * 8;
    long stride = (long)(gridDim.x - 64) * 256 * 8;
    for (long i = i0; i < n; i += stride) {
      f32x4 a = *reinterpret_cast<const f32x4*>(x + i);
      f32x4 b = *reinterpret_cast<const f32x4*>(x + i + 4);
      bf16x8 o;
      o[0] = f2bf(a[0]); o[1] = f2bf(a[1]); o[2] = f2bf(a[2]); o[3] = f2bf(a[3]);
      o[4] = f2bf(b[0]); o[5] = f2bf(b[1]); o[6] = f2bf(b[2]); o[7] = f2bf(b[3]);
      *reinterpret_cast<bf16x8*>(xb + i) = o;
    }
    return;
  }

  const int r = blockIdx.x;
  const float* D = oft_r + (size_t)r * 4096;

  for (int idx = tid; idx < 4096; idx += 256) {
    int i = idx >> 6, j = idx & 63;
    float s = 0.5f * (D[i * 64 + j] - D[j * 64 + i]);
    St[j][i] = s;
    Ta[i][j] = (i == j ? 1.0f : 0.0f) - s;   // T0 = I - S
  }
  __syncthreads();

  const int j = tid & 63;
  const int w = tid >> 6;
  float (*Tin)[65] = Ta;
  float (*Tout)[65] = Tb;

  for (int it = 0; it < 5; ++it) {           // final T = order-6 Neumann series
    float out[16];
#pragma unroll
    for (int m = 0; m < 16; ++m) out[m] = ((w * 16 + m) == j ? 1.0f : 0.0f);
    for (int c = 0; c < 64; ++c) {
      float tc = Tin[c][j];
      f32x4 s0 = *reinterpret_cast<const f32x4*>(&St[c][w * 16]);
      f32x4 s1 = *reinterpret_cast<const f32x4*>(&St[c][w * 16 + 4]);
      f32x4 s2 = *reinterpret_cast<const f32x4*>(&St[c][w * 16 + 8]);
      f32x4 s3 = *reinterpret_cast<const f32x4*>(&St[c][w * 16 + 12]);
#pragma unroll
      for (int q = 0; q < 4; ++q) {
        out[q]      -= s0[q] * tc;
        out[4 + q]  -= s1[q] * tc;
        out[8 + q]  -= s2[q] * tc;
        out[12 + q] -= s3[q] * tc;
      }
    }
#pragma unroll
    for (int m = 0; m < 16; ++m) Tout[w * 16 + m][j] = out[m];
    __syncthreads();
    float (*tmp)[65] = Tin; Tin = Tout; Tout = tmp;
  }
  {
    float out[16];
#pragma unroll
    for (int m = 0; m < 16; ++m) out[m] = Tin[w * 16 + m][j];
    for (int c = 0; c < 64; ++c) {
      float tc = Tin[c][j];
      f32x4 s0 = *reinterpret_cast<const f32x4*>(&St[c][w * 16]);
      f32x4 s1 = *reinterpret_cast<const f32x4*>(&St[c][w * 16 + 4]);
      f32x4 s2 = *reinterpret_cast<const f32x4*>(&St[c][w * 16 + 8]);
      f32x4 s3 = *reinterpret_cast<const f32x4*>(&St[c][w * 16 + 12]);
#pragma unroll
      for (int q = 0; q < 4; ++q) {
        out[q]      -= s0[q] * tc;
        out[4 + q]  -= s1[q] * tc;
        out[8 + q]  -= s2[q] * tc;
        out[12 + q] -= s3[q] * tc;
      }
    }
#pragma unroll
    for (int m = 0; m < 16; ++m) Qxt[(size_t)r * 4096 + (w * 16 + m) * 64 + j] = out[m];
  }
}

// ---------------- Kernel 2: fold rotation into W via MFMA (2048 blocks) ---------------
// Wp[o, r*64+k] = sum_c W[o, r*64+c] * Q[k][c]
__global__ __launch_bounds__(256) void fold_w_kernel(const float* __restrict__ W,
                                                     const float* __restrict__ Qxt,
                                                     bf16* __restrict__ Wp) {
  __shared__ bf16 Wb[128 * 64];
  __shared__ bf16 Xt[64 * 64];
  const int tid = threadIdx.x;
  const int lane = tid & 63;
  const int wave = tid >> 6;
  const int o0 = blockIdx.x * 128;
  const int r = blockIdx.y;
  const int fr = lane & 15;
  const int kg = lane >> 4;

#pragma unroll
  for (int i = 0; i < 8; ++i) {
    int c = i * 256 + tid;
    int row = c >> 4, c4 = c & 15;
    f32x4 v = *reinterpret_cast<const f32x4*>(W + (size_t)(o0 + row) * 4096 + r * 64 + c4 * 4);
    bf16x4 o; o[0] = f2bf(v[0]); o[1] = f2bf(v[1]); o[2] = f2bf(v[2]); o[3] = f2bf(v[3]);
    *reinterpret_cast<bf16x4*>(&Wb[row * 64 + c4 * 4]) = o;
  }
#pragma unroll
  for (int i = 0; i < 4; ++i) {
    int c = i * 256 + tid;
    int row = c >> 4, c4 = c & 15;
    f32x4 v = *reinterpret_cast<const f32x4*>(Qxt + (size_t)r * 4096 + row * 64 + c4 * 4);
    bf16x4 o; o[0] = f2bf(v[0]); o[1] = f2bf(v[1]); o[2] = f2bf(v[2]); o[3] = f2bf(v[3]);
    *reinterpret_cast<bf16x4*>(&Xt[row * 64 + c4 * 4]) = o;
  }
  __syncthreads();

  const int wm = wave * 32;
  f32x4 acc[2][4];
#pragma unroll
  for (int mi = 0; mi < 2; ++mi)
#pragma unroll
    for (int ni = 0; ni < 4; ++ni) acc[mi][ni] = (f32x4){0.f, 0.f, 0.f, 0.f};

#pragma unroll
  for (int kk = 0; kk < 64; kk += 32) {
    bf16x8 af[2], bx[4];
#pragma unroll
    for (int mi = 0; mi < 2; ++mi)
      af[mi] = *reinterpret_cast<const bf16x8*>(&Wb[(wm + mi * 16 + fr) * 64 + kk + kg * 8]);
#pragma unroll
    for (int ni = 0; ni < 4; ++ni)
      bx[ni] = *reinterpret_cast<const bf16x8*>(&Xt[(ni * 16 + fr) * 64 + kk + kg * 8]);
#pragma unroll
    for (int mi = 0; mi < 2; ++mi)
#pragma unroll
      for (int ni = 0; ni < 4; ++ni)
        acc[mi][ni] = __builtin_amdgcn_mfma_f32_16x16x32_bf16(af[mi], bx[ni], acc[mi][ni], 0, 0, 0);
  }

#pragma unroll
  for (int mi = 0; mi < 2; ++mi)
#pragma unroll
    for (int ni = 0; ni < 4; ++ni)
#pragma unroll
      for (int q = 0; q < 4; ++q) {
        int row = o0 + wm + mi * 16 + kg * 4 + q;
        int col = ni * 16 + fr;
        Wp[(size_t)row * 4096 + r * 64 + col] = f2bf(acc[mi][ni][q]);
      }
}

// ---------------- Kernel 3: 256x256 GEMM, 5-slot LDS ring, 1 barrier/phase -----------
// (r13 — proven 230us, conflicts 0)
// A=xb [M,K] bf16, B=Wp [N,K] bf16 (B^T layout), C [M,N] f32. 8 waves (2M x 4N).
// Ring: 5 slots x 32KB = 160 KiB. slot(t,ks) = (2t+ks)%5. Stage: P0 A(t+2,ks0),
// P1 B(t+2,ks0), P2 A(t+2,ks1), P3 B(t+2,ks1). Steady vmcnt(12) at P1/P3; tail 8/4, 0.
// Swizzle key (row>>1)&3 (conflict-free). Slot reuse distance 12 phases >> wave skew.

#define GLDS16(g, l) __builtin_amdgcn_global_load_lds( \
    (const __attribute__((address_space(1))) unsigned int*)(g), \
    (__attribute__((address_space(3))) unsigned int*)(l), 16, 0, 0)

#define VMCNT12 asm volatile("s_waitcnt vmcnt(12)" ::: "memory")
#define VMCNT8  asm volatile("s_waitcnt vmcnt(8)" ::: "memory")
#define VMCNT4  asm volatile("s_waitcnt vmcnt(4)" ::: "memory")
#define VMCNT0  asm volatile("s_waitcnt vmcnt(0)" ::: "memory")
#define NOWAIT  do {} while (0)
#define BARRIER() do { asm volatile("" ::: "memory"); \
  __builtin_amdgcn_s_barrier(); asm volatile("" ::: "memory"); } while (0)

#define MFMA16(AF, BF, RB) \
  _Pragma("unroll") \
  for (int m_ = 0; m_ < 4; ++m_) \
    _Pragma("unroll") \
    for (int n_ = 0; n_ < 4; ++n_) \
      acc[RB + m_][n_] = __builtin_amdgcn_mfma_f32_16x16x32_bf16(AF[m_], BF[n_], acc[RB + m_][n_], 0, 0, 0);

#define DO_T(S0, S1, SA, SB, TN, PRE, W2, W1) do { \
    /* P0: ks0 mi0-3; stage A(TN,ks0) */ \
    _Pragma("unroll") for (int n_ = 0; n_ < 4; ++n_) Ob[n_] = LDB(S0, n_); \
    _Pragma("unroll") for (int m_ = 0; m_ < 4; ++m_) Oa[m_] = LDA(S0, m_); \
    if (PRE) STG_A(TN, SA, 0); \
    BARRIER(); \
    __builtin_amdgcn_s_setprio(1); MFMA16(Oa, Ob, 0) __builtin_amdgcn_s_setprio(0); \
    /* P1: ks0 mi4-7; stage B(TN,ks0); W2 publishes (t,ks1) */ \
    _Pragma("unroll") for (int m_ = 0; m_ < 4; ++m_) Ea[m_] = LDA(S0, 4 + m_); \
    if (PRE) STG_B(TN, SA, 0); \
    W2; \
    BARRIER(); \
    __builtin_amdgcn_s_setprio(1); MFMA16(Ea, Ob, 4) __builtin_amdgcn_s_setprio(0); \
    /* P2: ks1 mi0-3; stage A(TN,ks1) */ \
    _Pragma("unroll") for (int n_ = 0; n_ < 4; ++n_) Eb[n_] = LDB(S1, n_); \
    _Pragma("unroll") for (int m_ = 0; m_ < 4; ++m_) Oa[m_] = LDA(S1, m_); \
    if (PRE) STG_A(TN, SB, 1); \
    BARRIER(); \
    __builtin_amdgcn_s_setprio(1); MFMA16(Oa, Eb, 0) __builtin_amdgcn_s_setprio(0); \
    /* P3: ks1 mi4-7; stage B(TN,ks1); W1 publishes (t+1,ks0) */ \
    _Pragma("unroll") for (int m_ = 0; m_ < 4; ++m_) Ea[m_] = LDA(S1, 4 + m_); \
    if (PRE) STG_B(TN, SB, 1); \
    W1; \
    BARRIER(); \
    __builtin_amdgcn_s_setprio(1); MFMA16(Ea, Eb, 4) __builtin_amdgcn_s_setprio(0); \
  } while (0)

__global__ __launch_bounds__(512, 2) void gemm_kernel(const bf16* __restrict__ A,
                                                      const bf16* __restrict__ B,
                                                      const float* __restrict__ bias,
                                                      float* __restrict__ C,
                                                      int M, int N, int K) {
  __shared__ bf16 lds[81920];   // 5 slots x 16384 elems = 160 KiB
  const int tid = threadIdx.x;
  const int lane = tid & 63;
  const int wave = tid >> 6;
  const int wr = wave >> 2;          // 0..1  (M)
  const int wc = wave & 3;           // 0..3  (N)
  const int fr = lane & 15;
  const int kg = lane >> 4;
  const int m0 = blockIdx.y * 256;
  const int n0 = blockIdx.x * 256;

  f32x4 acc[8][4];
#pragma unroll
  for (int m = 0; m < 8; ++m)
#pragma unroll
    for (int n = 0; n < 4; ++n) acc[m][n] = (f32x4){0.f, 0.f, 0.f, 0.f};

  auto STG = [&](const bf16* src, int base_row, int t, int ks, int ldsbase) {
#pragma unroll
    for (int i = 0; i < 2; ++i) {
      int c = i * 512 + tid;           // 1024 chunks of 16B per half-tile
      int row = c >> 2, cc = c & 3;
      const bf16* g = src + (size_t)(base_row + row) * K + t * 64 + ks * 32
                      + ((cc ^ ((row >> 1) & 3)) << 3);      // inverse-swizzled source
      GLDS16(g, &lds[ldsbase + ((i * 512 + wave * 64) << 3)]); // linear dest
    }
  };
  auto STG_A = [&](int t, int slot, int ks) { STG(A, m0, t, ks, slot * 16384); };
  auto STG_B = [&](int t, int slot, int ks) { STG(B, n0, t, ks, slot * 16384 + 8192); };

  auto LDA = [&](int slot, int mi) -> bf16x8 {
    int row = wr * 128 + mi * 16 + fr;
    return *reinterpret_cast<const bf16x8*>(
        &lds[slot * 16384 + row * 32 + ((kg ^ ((row >> 1) & 3)) << 3)]);
  };
  auto LDB = [&](int slot, int ni) -> bf16x8 {
    int row = wc * 64 + ni * 16 + fr;
    return *reinterpret_cast<const bf16x8*>(
        &lds[slot * 16384 + 8192 + row * 32 + ((kg ^ ((row >> 1) & 3)) << 3)]);
  };

  // prologue: stage tiles 0 and 1 in canonical FIFO order; publish (0,ks0).
  STG_A(0, 0, 0); STG_B(0, 0, 0); STG_A(0, 1, 1); STG_B(0, 1, 1);
  STG_A(1, 2, 0); STG_B(1, 2, 0); STG_A(1, 3, 1); STG_B(1, 3, 1);
  VMCNT12;
  BARRIER();

  bf16x8 Oa[4], Ob[4], Ea[4], Eb[4];
  // slots per 5-tile period: p0(0,1) p1(2,3) p2(4,0) p3(1,2) p4(3,4); SA/SB = slots of t+2.
  for (int t = 0; t < 60; t += 5) {
    DO_T(0, 1, 4, 0, t + 2, true, VMCNT12, VMCNT12);
    DO_T(2, 3, 1, 2, t + 3, true, VMCNT12, VMCNT12);
    DO_T(4, 0, 3, 4, t + 4, true, VMCNT12, VMCNT12);
    DO_T(1, 2, 0, 1, t + 5, true, VMCNT12, VMCNT12);
    DO_T(3, 4, 2, 3, t + 6, true, VMCNT12, VMCNT12);
  }
  // tail: tiles 60..63 (NT = 64)
  DO_T(0, 1, 4, 0, 62, true,  VMCNT12, VMCNT12);
  DO_T(2, 3, 1, 2, 63, true,  VMCNT12, VMCNT12);
  DO_T(4, 0, 0, 0, 0,  false, VMCNT8,  VMCNT4);
  DO_T(1, 2, 0, 0, 0,  false, VMCNT0,  NOWAIT);

  // epilogue: D row = kg*4+q (+16*m blocks), col = fr (+16*n)
#pragma unroll
  for (int n = 0; n < 4; ++n) {
    int col = n0 + wc * 64 + n * 16 + fr;
    float bv = bias[col];
#pragma unroll
    for (int m = 0; m < 8; ++m) {
      int row0 = m0 + wr * 128 + m * 16 + kg * 4;
#pragma unroll
      for (int q = 0; q < 4; ++q)
        C[(size_t)(row0 + q) * N + col] = acc[m][n][q] + bv;
    }
  }
}

extern "C" void kernel_launch(void* const* d_in, const int* in_sizes, int n_in,
                              void* d_out, int out_size, void* d_ws, size_t ws_size,
                              hipStream_t stream) {
  const float* x     = (const float*)d_in[0];   // [2,4096,4096]
  const float* oft_r = (const float*)d_in[1];   // [64,64,64]
  const float* W     = (const float*)d_in[2];   // [4096,4096]
  const float* b     = (const float*)d_in[3];   // [4096]
  float* y = (float*)d_out;                     // [8192,4096] f32

  char* ws = (char*)d_ws;
  float* Qxt = (float*)ws;                                 // 1 MiB: Q row-major per block
  bf16*  Wp  = (bf16*)(ws + (1u << 20));                   // 32 MiB: folded W, bf16
  bf16*  xb  = (bf16*)(ws + (1u << 20) + (32u << 20));     // 64 MiB: x, bf16

  prep_kernel<<<2112, 256, 0, stream>>>(oft_r, Qxt, x, xb, 33554432L);
  dim3 fg(32, 64);
  fold_w_kernel<<<fg, 256, 0, stream>>>(W, Qxt, Wp);
  dim3 gg(4096 / 256, 8192 / 256);   // (16, 32)
  gemm_kernel<<<gg, 512, 0, stream>>>(xb, Wp, b, y, 8192, 4096, 4096);
}

// Round 16
// 299.038 us; speedup vs baseline: 1.1397x; 1.0093x over previous
//
#include <hip/hip_runtime.h>
#include <hip/hip_bf16.h>
#include <stdint.h>

// GPTQOFTLinear: y = (x @ R_blockdiag) @ W^T + b
// W' = W with each 64-col block right-multiplied by Q_r^T; y = x @ W'^T + b.
// r16: BW-balanced prep. d1 = cayley(64) || cast x[0,0.75n)  (150 MB);
//      d2 = fold(2048)  || cast x[0.75n,n) (150 MB);  GEMM frozen (r13 ring, 228us).

typedef __bf16 bf16;
typedef __attribute__((ext_vector_type(4))) __bf16 bf16x4;
typedef __attribute__((ext_vector_type(8))) __bf16 bf16x8;
typedef __attribute__((ext_vector_type(4))) float f32x4;

__device__ __forceinline__ bf16 f2bf(float f) {
  unsigned u = __builtin_bit_cast(unsigned, f);
  u += 0x7fffu + ((u >> 16) & 1u);          // RNE
  unsigned short h = (unsigned short)(u >> 16);
  return __builtin_bit_cast(bf16, h);
}

// ---------------- Kernel 1: d1 = cayley (blocks 0-63) || cast x[0,n1) (blocks 64+) ----
__global__ __launch_bounds__(256) void prep_kernel(const float* __restrict__ oft_r,
                                                   float* __restrict__ Qxt,
                                                   const float* __restrict__ x,
                                                   bf16* __restrict__ xb, long n1) {
  __shared__ float St[64][68];
  __shared__ float Ta[64][65];
  __shared__ float Tb[64][65];
  const int tid = threadIdx.x;

  if (blockIdx.x >= 64) {
    long i0 = ((long)(blockIdx.x - 64) * 256 + tid) * 8;
    long stride = (long)(gridDim.x - 64) * 256 * 8;
    for (long i = i0; i < n1; i += stride) {
      f32x4 a = *reinterpret_cast<const f32x4*>(x + i);
      f32x4 b = *reinterpret_cast<const f32x4*>(x + i + 4);
      bf16x8 o;
      o[0] = f2bf(a[0]); o[1] = f2bf(a[1]); o[2] = f2bf(a[2]); o[3] = f2bf(a[3]);
      o[4] = f2bf(b[0]); o[5] = f2bf(b[1]); o[6] = f2bf(b[2]); o[7] = f2bf(b[3]);
      *reinterpret_cast<bf16x8*>(xb + i) = o;
    }
    return;
  }

  const int r = blockIdx.x;
  const float* D = oft_r + (size_t)r * 4096;

  for (int idx = tid; idx < 4096; idx += 256) {
    int i = idx >> 6, j = idx & 63;
    float s = 0.5f * (D[i * 64 + j] - D[j * 64 + i]);
    St[j][i] = s;
    Ta[i][j] = (i == j ? 1.0f : 0.0f) - s;   // T0 = I - S
  }
  __syncthreads();

  const int j = tid & 63;
  const int w = tid >> 6;
  float (*Tin)[65] = Ta;
  float (*Tout)[65] = Tb;

  for (int it = 0; it < 5; ++it) {           // final T = order-6 Neumann series
    float out[16];
#pragma unroll
    for (int m = 0; m < 16; ++m) out[m] = ((w * 16 + m) == j ? 1.0f : 0.0f);
    for (int c = 0; c < 64; ++c) {
      float tc = Tin[c][j];
      f32x4 s0 = *reinterpret_cast<const f32x4*>(&St[c][w * 16]);
      f32x4 s1 = *reinterpret_cast<const f32x4*>(&St[c][w * 16 + 4]);
      f32x4 s2 = *reinterpret_cast<const f32x4*>(&St[c][w * 16 + 8]);
      f32x4 s3 = *reinterpret_cast<const f32x4*>(&St[c][w * 16 + 12]);
#pragma unroll
      for (int q = 0; q < 4; ++q) {
        out[q]      -= s0[q] * tc;
        out[4 + q]  -= s1[q] * tc;
        out[8 + q]  -= s2[q] * tc;
        out[12 + q] -= s3[q] * tc;
      }
    }
#pragma unroll
    for (int m = 0; m < 16; ++m) Tout[w * 16 + m][j] = out[m];
    __syncthreads();
    float (*tmp)[65] = Tin; Tin = Tout; Tout = tmp;
  }
  {
    float out[16];
#pragma unroll
    for (int m = 0; m < 16; ++m) out[m] = Tin[w * 16 + m][j];
    for (int c = 0; c < 64; ++c) {
      float tc = Tin[c][j];
      f32x4 s0 = *reinterpret_cast<const f32x4*>(&St[c][w * 16]);
      f32x4 s1 = *reinterpret_cast<const f32x4*>(&St[c][w * 16 + 4]);
      f32x4 s2 = *reinterpret_cast<const f32x4*>(&St[c][w * 16 + 8]);
      f32x4 s3 = *reinterpret_cast<const f32x4*>(&St[c][w * 16 + 12]);
#pragma unroll
      for (int q = 0; q < 4; ++q) {
        out[q]      -= s0[q] * tc;
        out[4 + q]  -= s1[q] * tc;
        out[8 + q]  -= s2[q] * tc;
        out[12 + q] -= s3[q] * tc;
      }
    }
#pragma unroll
    for (int m = 0; m < 16; ++m) Qxt[(size_t)r * 4096 + (w * 16 + m) * 64 + j] = out[m];
  }
}

// ---------------- Kernel 2: d2 = fold (blocks 0-2047) || cast x[n1,n) (2048-4095) -----
// Fold: Wp[o, r*64+k] = sum_c W[o, r*64+c] * Q[k][c]; block b: o0=(b&31)*128, r=b>>5.
__global__ __launch_bounds__(256) void foldcast_kernel(const float* __restrict__ W,
                                                       const float* __restrict__ Qxt,
                                                       bf16* __restrict__ Wp,
                                                       const float* __restrict__ x,
                                                       bf16* __restrict__ xb,
                                                       long n1, long n) {
  __shared__ bf16 Wb[128 * 64];
  __shared__ bf16 Xt[64 * 64];
  const int tid = threadIdx.x;

  if (blockIdx.x >= 2048) {
    // ---- cast path: [n1, n) ----
    long i0 = n1 + ((long)(blockIdx.x - 2048) * 256 + tid) * 8;
    long stride = (long)(gridDim.x - 2048) * 256 * 8;
    for (long i = i0; i < n; i += stride) {
      f32x4 a = *reinterpret_cast<const f32x4*>(x + i);
      f32x4 b = *reinterpret_cast<const f32x4*>(x + i + 4);
      bf16x8 o;
      o[0] = f2bf(a[0]); o[1] = f2bf(a[1]); o[2] = f2bf(a[2]); o[3] = f2bf(a[3]);
      o[4] = f2bf(b[0]); o[5] = f2bf(b[1]); o[6] = f2bf(b[2]); o[7] = f2bf(b[3]);
      *reinterpret_cast<bf16x8*>(xb + i) = o;
    }
    return;
  }

  // ---- fold path ----
  const int lane = tid & 63;
  const int wave = tid >> 6;
  const int o0 = (blockIdx.x & 31) * 128;
  const int r = blockIdx.x >> 5;
  const int fr = lane & 15;
  const int kg = lane >> 4;

#pragma unroll
  for (int i = 0; i < 8; ++i) {
    int c = i * 256 + tid;
    int row = c >> 4, c4 = c & 15;
    f32x4 v = *reinterpret_cast<const f32x4*>(W + (size_t)(o0 + row) * 4096 + r * 64 + c4 * 4);
    bf16x4 o; o[0] = f2bf(v[0]); o[1] = f2bf(v[1]); o[2] = f2bf(v[2]); o[3] = f2bf(v[3]);
    *reinterpret_cast<bf16x4*>(&Wb[row * 64 + c4 * 4]) = o;
  }
#pragma unroll
  for (int i = 0; i < 4; ++i) {
    int c = i * 256 + tid;
    int row = c >> 4, c4 = c & 15;
    f32x4 v = *reinterpret_cast<const f32x4*>(Qxt + (size_t)r * 4096 + row * 64 + c4 * 4);
    bf16x4 o; o[0] = f2bf(v[0]); o[1] = f2bf(v[1]); o[2] = f2bf(v[2]); o[3] = f2bf(v[3]);
    *reinterpret_cast<bf16x4*>(&Xt[row * 64 + c4 * 4]) = o;
  }
  __syncthreads();

  const int wm = wave * 32;
  f32x4 acc[2][4];
#pragma unroll
  for (int mi = 0; mi < 2; ++mi)
#pragma unroll
    for (int ni = 0; ni < 4; ++ni) acc[mi][ni] = (f32x4){0.f, 0.f, 0.f, 0.f};

#pragma unroll
  for (int kk = 0; kk < 64; kk += 32) {
    bf16x8 af[2], bx[4];
#pragma unroll
    for (int mi = 0; mi < 2; ++mi)
      af[mi] = *reinterpret_cast<const bf16x8*>(&Wb[(wm + mi * 16 + fr) * 64 + kk + kg * 8]);
#pragma unroll
    for (int ni = 0; ni < 4; ++ni)
      bx[ni] = *reinterpret_cast<const bf16x8*>(&Xt[(ni * 16 + fr) * 64 + kk + kg * 8]);
#pragma unroll
    for (int mi = 0; mi < 2; ++mi)
#pragma unroll
      for (int ni = 0; ni < 4; ++ni)
        acc[mi][ni] = __builtin_amdgcn_mfma_f32_16x16x32_bf16(af[mi], bx[ni], acc[mi][ni], 0, 0, 0);
  }

#pragma unroll
  for (int mi = 0; mi < 2; ++mi)
#pragma unroll
    for (int ni = 0; ni < 4; ++ni)
#pragma unroll
      for (int q = 0; q < 4; ++q) {
        int row = o0 + wm + mi * 16 + kg * 4 + q;
        int col = ni * 16 + fr;
        Wp[(size_t)row * 4096 + r * 64 + col] = f2bf(acc[mi][ni][q]);
      }
}

// ---------------- Kernel 3: 256x256 GEMM, 5-slot LDS ring, 1 barrier/phase -----------
// (frozen: r13/r15 — 228us, MfmaUtil 58, conflicts 0)

#define GLDS16(g, l) __builtin_amdgcn_global_load_lds( \
    (const __attribute__((address_space(1))) unsigned int*)(g), \
    (__attribute__((address_space(3))) unsigned int*)(l), 16, 0, 0)

#define VMCNT12 asm volatile("s_waitcnt vmcnt(12)" ::: "memory")
#define VMCNT8  asm volatile("s_waitcnt vmcnt(8)" ::: "memory")
#define VMCNT4  asm volatile("s_waitcnt vmcnt(4)" ::: "memory")
#define VMCNT0  asm volatile("s_waitcnt vmcnt(0)" ::: "memory")
#define NOWAIT  do {} while (0)
#define BARRIER() do { asm volatile("" ::: "memory"); \
  __builtin_amdgcn_s_barrier(); asm volatile("" ::: "memory"); } while (0)

#define MFMA16(AF, BF, RB) \
  _Pragma("unroll") \
  for (int m_ = 0; m_ < 4; ++m_) \
    _Pragma("unroll") \
    for (int n_ = 0; n_ < 4; ++n_) \
      acc[RB + m_][n_] = __builtin_amdgcn_mfma_f32_16x16x32_bf16(AF[m_], BF[n_], acc[RB + m_][n_], 0, 0, 0);

#define DO_T(S0, S1, SA, SB, TN, PRE, W2, W1) do { \
    /* P0: ks0 mi0-3; stage A(TN,ks0) */ \
    _Pragma("unroll") for (int n_ = 0; n_ < 4; ++n_) Ob[n_] = LDB(S0, n_); \
    _Pragma("unroll") for (int m_ = 0; m_ < 4; ++m_) Oa[m_] = LDA(S0, m_); \
    if (PRE) STG_A(TN, SA, 0); \
    BARRIER(); \
    __builtin_amdgcn_s_setprio(1); MFMA16(Oa, Ob, 0) __builtin_amdgcn_s_setprio(0); \
    /* P1: ks0 mi4-7; stage B(TN,ks0); W2 publishes (t,ks1) */ \
    _Pragma("unroll") for (int m_ = 0; m_ < 4; ++m_) Ea[m_] = LDA(S0, 4 + m_); \
    if (PRE) STG_B(TN, SA, 0); \
    W2; \
    BARRIER(); \
    __builtin_amdgcn_s_setprio(1); MFMA16(Ea, Ob, 4) __builtin_amdgcn_s_setprio(0); \
    /* P2: ks1 mi0-3; stage A(TN,ks1) */ \
    _Pragma("unroll") for (int n_ = 0; n_ < 4; ++n_) Eb[n_] = LDB(S1, n_); \
    _Pragma("unroll") for (int m_ = 0; m_ < 4; ++m_) Oa[m_] = LDA(S1, m_); \
    if (PRE) STG_A(TN, SB, 1); \
    BARRIER(); \
    __builtin_amdgcn_s_setprio(1); MFMA16(Oa, Eb, 0) __builtin_amdgcn_s_setprio(0); \
    /* P3: ks1 mi4-7; stage B(TN,ks1); W1 publishes (t+1,ks0) */ \
    _Pragma("unroll") for (int m_ = 0; m_ < 4; ++m_) Ea[m_] = LDA(S1, 4 + m_); \
    if (PRE) STG_B(TN, SB, 1); \
    W1; \
    BARRIER(); \
    __builtin_amdgcn_s_setprio(1); MFMA16(Ea, Eb, 4) __builtin_amdgcn_s_setprio(0); \
  } while (0)

__global__ __launch_bounds__(512, 2) void gemm_kernel(const bf16* __restrict__ A,
                                                      const bf16* __restrict__ B,
                                                      const float* __restrict__ bias,
                                                      float* __restrict__ C,
                                                      int M, int N, int K) {
  __shared__ bf16 lds[81920];   // 5 slots x 16384 elems = 160 KiB
  const int tid = threadIdx.x;
  const int lane = tid & 63;
  const int wave = tid >> 6;
  const int wr = wave >> 2;          // 0..1  (M)
  const int wc = wave & 3;           // 0..3  (N)
  const int fr = lane & 15;
  const int kg = lane >> 4;
  const int m0 = blockIdx.y * 256;
  const int n0 = blockIdx.x * 256;

  f32x4 acc[8][4];
#pragma unroll
  for (int m = 0; m < 8; ++m)
#pragma unroll
    for (int n = 0; n < 4; ++n) acc[m][n] = (f32x4){0.f, 0.f, 0.f, 0.f};

  auto STG = [&](const bf16* src, int base_row, int t, int ks, int ldsbase) {
#pragma unroll
    for (int i = 0; i < 2; ++i) {
      int c = i * 512 + tid;           // 1024 chunks of 16B per half-tile
      int row = c >> 2, cc = c & 3;
      const bf16* g = src + (size_t)(base_row + row) * K + t * 64 + ks * 32
                      + ((cc ^ ((row >> 1) & 3)) << 3);      // inverse-swizzled source
      GLDS16(g, &lds[ldsbase + ((i * 512 + wave * 64) << 3)]); // linear dest
    }
  };
  auto STG_A = [&](int t, int slot, int ks) { STG(A, m0, t, ks, slot * 16384); };
  auto STG_B = [&](int t, int slot, int ks) { STG(B, n0, t, ks, slot * 16384 + 8192); };

  auto LDA = [&](int slot, int mi) -> bf16x8 {
    int row = wr * 128 + mi * 16 + fr;
    return *reinterpret_cast<const bf16x8*>(
        &lds[slot * 16384 + row * 32 + ((kg ^ ((row >> 1) & 3)) << 3)]);
  };
  auto LDB = [&](int slot, int ni) -> bf16x8 {
    int row = wc * 64 + ni * 16 + fr;
    return *reinterpret_cast<const bf16x8*>(
        &lds[slot * 16384 + 8192 + row * 32 + ((kg ^ ((row >> 1) & 3)) << 3)]);
  };

  // prologue: stage tiles 0 and 1 in canonical FIFO order; publish (0,ks0).
  STG_A(0, 0, 0); STG_B(0, 0, 0); STG_A(0, 1, 1); STG_B(0, 1, 1);
  STG_A(1, 2, 0); STG_B(1, 2, 0); STG_A(1, 3, 1); STG_B(1, 3, 1);
  VMCNT12;
  BARRIER();

  bf16x8 Oa[4], Ob[4], Ea[4], Eb[4];
  // slots per 5-tile period: p0(0,1) p1(2,3) p2(4,0) p3(1,2) p4(3,4); SA/SB = slots of t+2.
  for (int t = 0; t < 60; t += 5) {
    DO_T(0, 1, 4, 0, t + 2, true, VMCNT12, VMCNT12);
    DO_T(2, 3, 1, 2, t + 3, true, VMCNT12, VMCNT12);
    DO_T(4, 0, 3, 4, t + 4, true, VMCNT12, VMCNT12);
    DO_T(1, 2, 0, 1, t + 5, true, VMCNT12, VMCNT12);
    DO_T(3, 4, 2, 3, t + 6, true, VMCNT12, VMCNT12);
  }
  // tail: tiles 60..63 (NT = 64)
  DO_T(0, 1, 4, 0, 62, true,  VMCNT12, VMCNT12);
  DO_T(2, 3, 1, 2, 63, true,  VMCNT12, VMCNT12);
  DO_T(4, 0, 0, 0, 0,  false, VMCNT8,  VMCNT4);
  DO_T(1, 2, 0, 0, 0,  false, VMCNT0,  NOWAIT);

  // epilogue: D row = kg*4+q (+16*m blocks), col = fr (+16*n)
#pragma unroll
  for (int n = 0; n < 4; ++n) {
    int col = n0 + wc * 64 + n * 16 + fr;
    float bv = bias[col];
#pragma unroll
    for (int m = 0; m < 8; ++m) {
      int row0 = m0 + wr * 128 + m * 16 + kg * 4;
#pragma unroll
      for (int q = 0; q < 4; ++q)
        C[(size_t)(row0 + q) * N + col] = acc[m][n][q] + bv;
    }
  }
}

extern "C" void kernel_launch(void* const* d_in, const int* in_sizes, int n_in,
                              void* d_out, int out_size, void* d_ws, size_t ws_size,
                              hipStream_t stream) {
  const float* x     = (const float*)d_in[0];   // [2,4096,4096]
  const float* oft_r = (const float*)d_in[1];   // [64,64,64]
  const float* W     = (const float*)d_in[2];   // [4096,4096]
  const float* b     = (const float*)d_in[3];   // [4096]
  float* y = (float*)d_out;                     // [8192,4096] f32

  char* ws = (char*)d_ws;
  float* Qxt = (float*)ws;                                 // 1 MiB: Q row-major per block
  bf16*  Wp  = (bf16*)(ws + (1u << 20));                   // 32 MiB: folded W, bf16
  bf16*  xb  = (bf16*)(ws + (1u << 20) + (32u << 20));     // 64 MiB: x, bf16

  const long n  = 33554432L;            // total x elements
  const long n1 = 25165824L;            // 0.75*n — BW-balance split point

  prep_kernel<<<2112, 256, 0, stream>>>(oft_r, Qxt, x, xb, n1);
  foldcast_kernel<<<4096, 256, 0, stream>>>(W, Qxt, Wp, x, xb, n1, n);
  dim3 gg(4096 / 256, 8192 / 256);   // (16, 32)
  gemm_kernel<<<gg, 512, 0, stream>>>(xb, Wp, b, y, 8192, 4096, 4096);
}